// Round 6
// baseline (187.418 us; speedup 1.0000x reference)
//
#include <hip/hip_runtime.h>
#include <stdint.h>

#define NB 4
#define NH 16
#define DKH 64
#define DMODEL 1024
#define SEQ 1024
#define SCALE 0.125f
#define NEG_INF -1.0e9f
#define K2E 0.18033688011112042f  // SCALE * log2(e): softmax in exp2 domain

typedef __bf16 bf16_t;
typedef __bf16 bf16x8 __attribute__((ext_vector_type(8)));
typedef __bf16 bf16x4v __attribute__((ext_vector_type(4)));
typedef float f32x4 __attribute__((ext_vector_type(4)));

typedef const uint32_t __attribute__((address_space(1)))* gas_ptr;
typedef uint32_t __attribute__((address_space(3)))* las_ptr;

// async global->LDS, 16B per lane, dest = wave-uniform base + lane*16
__device__ __forceinline__ void gload_lds16(const void* g, void* l) {
  __builtin_amdgcn_global_load_lds((gas_ptr)g, (las_ptr)l, 16, 0, 0);
}

// T2 XOR swizzle for [R][64] bf16 tiles (128B rows): element col ^= (row&7)<<3.
// Staging keeps LDS dest linear and pre-swizzles the GLOBAL source column;
// all LDS reads / reg->LDS writes apply the same XOR (both-sides involution).
// Proven: SQ_LDS_BANK_CONFLICT 1.99e7 -> 0 (R1->R2).
//
// __launch_bounds__ NOTE (R4 post-mortem): (256,4) squeezed to 64 VGPR and
// spilled (~230MB scratch, WRITE_SIZE 8->118MB). (256,2) proven sane.

// ---------------- f32 -> bf16 conversion (select tensor by blockIdx.y) ----
__global__ void cvt_multi(const float* __restrict__ i0, const float* __restrict__ i1,
                          const float* __restrict__ i2, const float* __restrict__ i3,
                          const float* __restrict__ i4, const float* __restrict__ i5,
                          bf16_t* o0, bf16_t* o1, bf16_t* o2, bf16_t* o3, bf16_t* o4, bf16_t* o5,
                          int n) {
  const int t = blockIdx.y;
  const float* in = (t == 0) ? i0 : (t == 1) ? i1 : (t == 2) ? i2 : (t == 3) ? i3 : (t == 4) ? i4 : i5;
  bf16_t* out = (t == 0) ? o0 : (t == 1) ? o1 : (t == 2) ? o2 : (t == 3) ? o3 : (t == 4) ? o4 : o5;
  const int idx = (blockIdx.x * 256 + threadIdx.x) * 4;
  if (idx >= n) return;
  const float4 v = *(const float4*)(in + idx);
  bf16x4v p;
  p[0] = (bf16_t)v.x; p[1] = (bf16_t)v.y; p[2] = (bf16_t)v.z; p[3] = (bf16_t)v.w;
  *(bf16x4v*)(out + idx) = p;
}

// ---------------- 128x128-tile GEMM core (m97 structure) -------------------
// Y = A @ W^T (+bias). 4 waves (2x2), each owns 64x64; acc[4][4]; BK=64.
// MODE 0: bf16 head-split [B,H,L,DK]; MODE 1: bf16 [B,H,DK,L]; MODE 2: f32.
#define NXE ((size_t)NB * SEQ * DMODEL)      // elements per X/out segment
#define NWE ((size_t)DMODEL * DMODEL)

template<int MODE>
__device__ __forceinline__ void gemm128_body(
    const bf16_t* __restrict__ A, const bf16_t* __restrict__ W,
    const float* __restrict__ bias, void* __restrict__ outp,
    int m0, int n0, bf16_t* As, bf16_t* Bs) {
  const int tid = threadIdx.x;
  const int lane = tid & 63;
  const int w = tid >> 6;
  const int wm = w >> 1, wn = w & 1;
  const int g = lane >> 4, c = lane & 15;
  const int lrow = lane >> 3;
  const int lcol = ((lane & 7) * 8) ^ ((lane >> 3) << 3);  // pre-swizzled source col
  const int sc = (c & 7) << 3;                             // read-side XOR

  f32x4 acc[4][4] = {};

  for (int kt = 0; kt < DMODEL; kt += 64) {
#pragma unroll
    for (int p = 0; p < 4; ++p) {
      const int row = w * 32 + p * 8;
      gload_lds16(A + (size_t)(m0 + row + lrow) * DMODEL + kt + lcol, &As[row * 64]);
      gload_lds16(W + (size_t)(n0 + row + lrow) * DMODEL + kt + lcol, &Bs[row * 64]);
    }
    __syncthreads();
    bf16x8 af[4][2], bfr[4][2];
#pragma unroll
    for (int i = 0; i < 4; ++i)
#pragma unroll
      for (int kk = 0; kk < 2; ++kk) {
        af[i][kk]  = *(const bf16x8*)&As[(wm * 64 + i * 16 + c) * 64 + ((kk * 32 + g * 8) ^ sc)];
        bfr[i][kk] = *(const bf16x8*)&Bs[(wn * 64 + i * 16 + c) * 64 + ((kk * 32 + g * 8) ^ sc)];
      }
#pragma unroll
    for (int i = 0; i < 4; ++i)
#pragma unroll
      for (int j = 0; j < 4; ++j) {
        acc[i][j] = __builtin_amdgcn_mfma_f32_16x16x32_bf16(af[i][0], bfr[j][0], acc[i][j], 0, 0, 0);
        acc[i][j] = __builtin_amdgcn_mfma_f32_16x16x32_bf16(af[i][1], bfr[j][1], acc[i][j], 0, 0, 0);
      }
    __syncthreads();
  }

  float bv4[4];
#pragma unroll
  for (int j = 0; j < 4; ++j) bv4[j] = bias[n0 + wn * 64 + j * 16 + c];

#pragma unroll
  for (int i = 0; i < 4; ++i) {
    const int mrow = m0 + wm * 64 + i * 16 + g * 4;   // C-layout: row = g*4 + r
    const int b_ = mrow >> 10, l_ = mrow & 1023;
#pragma unroll
    for (int j = 0; j < 4; ++j) {
      const int n = n0 + wn * 64 + j * 16 + c;        // C-layout: col = lane&15
      if (MODE == 2) {
        float* o = (float*)outp;
#pragma unroll
        for (int r = 0; r < 4; ++r)
          o[(size_t)(mrow + r) * DMODEL + n] = acc[i][j][r] + bv4[j];
      } else if (MODE == 0) {
        bf16_t* o = (bf16_t*)outp;
        const int h_ = n >> 6, dk_ = n & 63;
#pragma unroll
        for (int r = 0; r < 4; ++r)
          o[((size_t)(b_ * NH + h_) * SEQ + l_ + r) * DKH + dk_] =
              (bf16_t)(acc[i][j][r] + bv4[j]);
      } else { // MODE 1: transposed [B,H,DK,L]; 4 consecutive l -> packed 8B store
        bf16_t* o = (bf16_t*)outp;
        const int h_ = n >> 6, dk_ = n & 63;
        bf16x4v pk;
#pragma unroll
        for (int r = 0; r < 4; ++r) pk[r] = (bf16_t)(acc[i][j][r] + bv4[j]);
        *(bf16x4v*)&o[((size_t)(b_ * NH + h_) * DKH + dk_) * SEQ + l_] = pk;
      }
    }
  }
}

// grouped projection: 5 segments x (32 m-tiles x 8 n-tiles) = 1280 blocks
__global__ void __launch_bounds__(256, 2)
proj_gemm(const bf16_t* __restrict__ Xbase, const bf16_t* __restrict__ Wbase,
          bf16_t* __restrict__ Obase,
          const float* __restrict__ b0, const float* __restrict__ b1,
          const float* __restrict__ b2, const float* __restrict__ b3,
          const float* __restrict__ b4) {
  __shared__ bf16_t As[128 * 64];
  __shared__ bf16_t Bs[128 * 64];
  const int bid = blockIdx.x;
  const int lid = (bid & 7) * 160 + (bid >> 3);   // T1 swizzle (1280 % 8 == 0)
  const int seg = lid >> 8;                       // 0..4
  const int rr = lid & 255;
  const int m0 = (rr >> 3) * 128, n0 = (rr & 7) * 128;

  const bf16_t* A = Xbase + (size_t)((seg < 3) ? seg : 3) * NXE;
  const bf16_t* W = Wbase + (size_t)seg * NWE;
  const int ooff = (seg == 0) ? 0 : (seg == 1) ? 1 : (seg == 2) ? 3 : (seg == 3) ? 2 : 4;
  bf16_t* out = Obase + (size_t)ooff * NXE;
  const float* bias = (seg == 0) ? b0 : (seg == 1) ? b1 : (seg == 2) ? b2 : (seg == 3) ? b3 : b4;

  if (seg == 2 || seg == 4) gemm128_body<1>(A, W, bias, out, m0, n0, As, Bs);
  else                      gemm128_body<0>(A, W, bias, out, m0, n0, As, Bs);
}

// output projection -> f32 d_out: 32 x 8 = 256 blocks
__global__ void __launch_bounds__(256, 2)
out_gemm(const bf16_t* __restrict__ A, const bf16_t* __restrict__ W,
         const float* __restrict__ bias, float* __restrict__ out) {
  __shared__ bf16_t As[128 * 64];
  __shared__ bf16_t Bs[128 * 64];
  const int bid = blockIdx.x;
  const int lid = (bid & 7) * 32 + (bid >> 3);    // T1 swizzle (256 % 8 == 0)
  const int m0 = (lid >> 3) * 128, n0 = (lid & 7) * 128;
  gemm128_body<2>(A, W, bias, out, m0, n0, As, Bs);
}

// ---------------- fused dual flash attention (swapped QK^T, interleaved) ---
// S^T = mfma(A=K, B=Q): lane (g,c) holds S[kv=f*16+g*4+r][q=c]; softmax is
// lane-local + 2 cross-g shfl. Both branches (vis/rel) computed per tile in
// one interleaved block: QKv+QKr (16 MFMA) | SMv | SMr (VALU) | PVv+PVr
// (16 MFMA). Separate per-wave P buffers so no LDS aliasing serializes.
__global__ void __launch_bounds__(256, 2)
attn_kernel(const bf16_t* __restrict__ q, const bf16_t* __restrict__ k,
            const bf16_t* __restrict__ rk, const bf16_t* __restrict__ vT,
            const bf16_t* __restrict__ rvT, const int* __restrict__ mask,
            bf16_t* __restrict__ x) {
  __shared__ bf16_t Ks[64 * 64], RKs[64 * 64], Vs[64 * 64], RVs[64 * 64]; // 32KB
  __shared__ bf16_t Ps[8][16 * 64];                                      // 16KB

  const int tid = threadIdx.x;
  const int lane = tid & 63;
  const int w = tid >> 6;
  const int g = lane >> 4, c = lane & 15;
  const int sc = (c & 7) << 3;
  const int bid = blockIdx.x;
  const int lid = (bid & 7) * 128 + (bid >> 3);  // T1 swizzle (1024 % 8 == 0)
  const int qt = lid & 15;
  const int bh = lid >> 4;
  const int b = bh >> 4, h = bh & 15;
  const int q0 = qt * 64;

  const bf16_t* qp = q + (size_t)bh * SEQ * DKH;
  const bf16_t* kp = k + (size_t)bh * SEQ * DKH;
  const bf16_t* rkp = rk + (size_t)bh * SEQ * DKH;
  const bf16_t* vp = vT + (size_t)bh * DKH * SEQ;
  const bf16_t* rvp = rvT + (size_t)bh * DKH * SEQ;
  const int* mp = mask + b * SEQ;
  const int lrow = lane >> 3;
  const int lcol = ((lane & 7) * 8) ^ ((lane >> 3) << 3);  // pre-swizzled source col

  bf16_t* Pv = Ps[w * 2];
  bf16_t* Pr = Ps[w * 2 + 1];

  // Q fragments in registers (wave owns 16 q-rows; B-operand layout)
  bf16x8 qf[2];
#pragma unroll
  for (int kk = 0; kk < 2; ++kk)
    qf[kk] = *(const bf16x8*)(qp + (size_t)(q0 + w * 16 + c) * DKH + kk * 32 + g * 8);

  f32x4 ov[4] = {}, orl[4] = {};
  float mv = NEG_INF, mr = NEG_INF, lv = 0.f, lr = 0.f;

  for (int t = 0; t < 16; ++t) {
    const int kv0 = t * 64;
    if (t) __syncthreads();   // previous compute done before overwriting tiles
#pragma unroll
    for (int p = 0; p < 2; ++p) {
      const int row = w * 16 + p * 8;
      gload_lds16(kp  + (size_t)(kv0 + row + lrow) * DKH + lcol, &Ks[row * 64]);
      gload_lds16(rkp + (size_t)(kv0 + row + lrow) * DKH + lcol, &RKs[row * 64]);
      gload_lds16(vp  + (size_t)(row + lrow) * SEQ + kv0 + lcol, &Vs[row * 64]);
      gload_lds16(rvp + (size_t)(row + lrow) * SEQ + kv0 + lcol, &RVs[row * 64]);
    }
    __syncthreads();          // tiles ready (TLP across blocks hides this)

    int4 mk4[4];
#pragma unroll
    for (int f = 0; f < 4; ++f) mk4[f] = *(const int4*)&mp[kv0 + f * 16 + g * 4];

    // ---- QK^T for BOTH branches (contiguous MFMA block) ----
    f32x4 sv[4], sr[4];
#pragma unroll
    for (int f = 0; f < 4; ++f) {
      const bf16x8 k0  = *(const bf16x8*)&Ks [(f * 16 + c) * 64 + ((g * 8) ^ sc)];
      const bf16x8 k1  = *(const bf16x8*)&Ks [(f * 16 + c) * 64 + ((32 + g * 8) ^ sc)];
      const bf16x8 rk0 = *(const bf16x8*)&RKs[(f * 16 + c) * 64 + ((g * 8) ^ sc)];
      const bf16x8 rk1 = *(const bf16x8*)&RKs[(f * 16 + c) * 64 + ((32 + g * 8) ^ sc)];
      f32x4 a = {0.f, 0.f, 0.f, 0.f};
      a = __builtin_amdgcn_mfma_f32_16x16x32_bf16(k0, qf[0], a, 0, 0, 0);
      a = __builtin_amdgcn_mfma_f32_16x16x32_bf16(k1, qf[1], a, 0, 0, 0);
      sv[f] = a;
      f32x4 ar = {0.f, 0.f, 0.f, 0.f};
      ar = __builtin_amdgcn_mfma_f32_16x16x32_bf16(rk0, qf[0], ar, 0, 0, 0);
      ar = __builtin_amdgcn_mfma_f32_16x16x32_bf16(rk1, qf[1], ar, 0, 0, 0);
      sr[f] = ar;
    }

    // ---- mask + scale (exp2 domain) both branches ----
#pragma unroll
    for (int f = 0; f < 4; ++f) {
      const int4 m4 = mk4[f];
      sv[f][0] = (m4.x == 0) ? NEG_INF : sv[f][0] * K2E;
      sv[f][1] = (m4.y == 0) ? NEG_INF : sv[f][1] * K2E;
      sv[f][2] = (m4.z == 0) ? NEG_INF : sv[f][2] * K2E;
      sv[f][3] = (m4.w == 0) ? NEG_INF : sv[f][3] * K2E;
      sr[f][0] = (m4.x == 0) ? NEG_INF : sr[f][0] * K2E;
      sr[f][1] = (m4.y == 0) ? NEG_INF : sr[f][1] * K2E;
      sr[f][2] = (m4.z == 0) ? NEG_INF : sr[f][2] * K2E;
      sr[f][3] = (m4.w == 0) ? NEG_INF : sr[f][3] * K2E;
    }

    // ---- softmax vis ----
    {
      float tm = fmaxf(fmaxf(sv[0][0], sv[0][1]), fmaxf(sv[0][2], sv[0][3]));
#pragma unroll
      for (int f = 1; f < 4; ++f)
        tm = fmaxf(tm, fmaxf(fmaxf(sv[f][0], sv[f][1]), fmaxf(sv[f][2], sv[f][3])));
      tm = fmaxf(tm, __shfl_xor(tm, 16));
      tm = fmaxf(tm, __shfl_xor(tm, 32));
      const float mnew = fmaxf(mv, tm);
      const float sf = __builtin_amdgcn_exp2f(mv - mnew);
      mv = mnew;
      float pf = 0.f;
#pragma unroll
      for (int f = 0; f < 4; ++f) {
        bf16x4v pk;
#pragma unroll
        for (int r = 0; r < 4; ++r) {
          const float p = __builtin_amdgcn_exp2f(sv[f][r] - mnew);
          pf += p;
          pk[r] = (bf16_t)p;
        }
        *(bf16x4v*)&Pv[c * 64 + ((f * 16 + g * 4) ^ sc)] = pk;
      }
      lv = lv * sf + pf;
#pragma unroll
      for (int jd = 0; jd < 4; ++jd)
#pragma unroll
        for (int r = 0; r < 4; ++r) ov[jd][r] *= sf;
    }

    // ---- softmax rel ----
    {
      float tm = fmaxf(fmaxf(sr[0][0], sr[0][1]), fmaxf(sr[0][2], sr[0][3]));
#pragma unroll
      for (int f = 1; f < 4; ++f)
        tm = fmaxf(tm, fmaxf(fmaxf(sr[f][0], sr[f][1]), fmaxf(sr[f][2], sr[f][3])));
      tm = fmaxf(tm, __shfl_xor(tm, 16));
      tm = fmaxf(tm, __shfl_xor(tm, 32));
      const float mnew = fmaxf(mr, tm);
      const float sf = __builtin_amdgcn_exp2f(mr - mnew);
      mr = mnew;
      float pf = 0.f;
#pragma unroll
      for (int f = 0; f < 4; ++f) {
        bf16x4v pk;
#pragma unroll
        for (int r = 0; r < 4; ++r) {
          const float p = __builtin_amdgcn_exp2f(sr[f][r] - mnew);
          pf += p;
          pk[r] = (bf16_t)p;
        }
        *(bf16x4v*)&Pr[c * 64 + ((f * 16 + g * 4) ^ sc)] = pk;
      }
      lr = lr * sf + pf;
#pragma unroll
      for (int jd = 0; jd < 4; ++jd)
#pragma unroll
        for (int r = 0; r < 4; ++r) orl[jd][r] *= sf;
    }

    // ---- PV for BOTH branches (contiguous MFMA block) ----
    const bf16x8 pav0 = *(const bf16x8*)&Pv[c * 64 + ((g * 8) ^ sc)];
    const bf16x8 pav1 = *(const bf16x8*)&Pv[c * 64 + ((32 + g * 8) ^ sc)];
    const bf16x8 par0 = *(const bf16x8*)&Pr[c * 64 + ((g * 8) ^ sc)];
    const bf16x8 par1 = *(const bf16x8*)&Pr[c * 64 + ((32 + g * 8) ^ sc)];
#pragma unroll
    for (int jd = 0; jd < 4; ++jd) {
      const bf16x8 v0  = *(const bf16x8*)&Vs [(jd * 16 + c) * 64 + ((g * 8) ^ sc)];
      const bf16x8 v1  = *(const bf16x8*)&Vs [(jd * 16 + c) * 64 + ((32 + g * 8) ^ sc)];
      ov[jd]  = __builtin_amdgcn_mfma_f32_16x16x32_bf16(v0, pav0, ov[jd], 0, 0, 0);
      ov[jd]  = __builtin_amdgcn_mfma_f32_16x16x32_bf16(v1, pav1, ov[jd], 0, 0, 0);
      const bf16x8 rv0 = *(const bf16x8*)&RVs[(jd * 16 + c) * 64 + ((g * 8) ^ sc)];
      const bf16x8 rv1 = *(const bf16x8*)&RVs[(jd * 16 + c) * 64 + ((32 + g * 8) ^ sc)];
      orl[jd] = __builtin_amdgcn_mfma_f32_16x16x32_bf16(rv0, par0, orl[jd], 0, 0, 0);
      orl[jd] = __builtin_amdgcn_mfma_f32_16x16x32_bf16(rv1, par1, orl[jd], 0, 0, 0);
    }
  }

  // denominators: reduce per-lane partials across the 4 g-groups
  lv += __shfl_xor(lv, 16); lv += __shfl_xor(lv, 32);
  lr += __shfl_xor(lr, 16); lr += __shfl_xor(lr, 32);
  const float rlv = 1.0f / lv, rlr = 1.0f / lr;

  bf16_t* xb = x + (size_t)b * SEQ * DMODEL + (size_t)h * DKH;
  const int qrow = q0 + w * 16 + c;
#pragma unroll
  for (int jd = 0; jd < 4; ++jd) {
    bf16x4v pk;
#pragma unroll
    for (int r = 0; r < 4; ++r)
      pk[r] = (bf16_t)(ov[jd][r] * rlv + orl[jd][r] * rlr);
    *(bf16x4v*)&xb[(size_t)qrow * DMODEL + jd * 16 + g * 4] = pk;
  }
}

// ---------------- host launch ---------------------------------------------
extern "C" void kernel_launch(void* const* d_in, const int* in_sizes, int n_in,
                              void* d_out, int out_size, void* d_ws, size_t ws_size,
                              hipStream_t stream) {
  (void)in_sizes; (void)n_in; (void)out_size; (void)ws_size;
  const float* query = (const float*)d_in[0];
  const float* key_  = (const float*)d_in[1];
  const float* value = (const float*)d_in[2];
  const float* weak  = (const float*)d_in[3];
  const int*   mask  = (const int*)d_in[4];
  const float* Wq  = (const float*)d_in[5];  const float* bq  = (const float*)d_in[6];
  const float* Wk  = (const float*)d_in[7];  const float* bk  = (const float*)d_in[8];
  const float* Wv  = (const float*)d_in[9];  const float* bv  = (const float*)d_in[10];
  const float* Wrk = (const float*)d_in[11]; const float* brk = (const float*)d_in[12];
  const float* Wrv = (const float*)d_in[13]; const float* brv = (const float*)d_in[14];
  const float* Wo  = (const float*)d_in[15]; const float* bo  = (const float*)d_in[16];

  char* ws = (char*)d_ws;
  size_t off = 0;
  auto alloc = [&](size_t bytes) {
    void* p = ws + off;
    off += (bytes + 255) & ~(size_t)255;
    return p;
  };
  const size_t SZ_X = NXE * sizeof(bf16_t); // 8 MB (256-aligned -> contiguous)
  const size_t SZ_W = NWE * sizeof(bf16_t); // 2 MB

  // X segments contiguous (q,k,v,r), W segments contiguous (q,k,v,rk,rv,o),
  // proj outputs contiguous (qh,kh,rkh,vTh,rvTh) -- proj_gemm indexes by base.
  bf16_t* Xq = (bf16_t*)alloc(SZ_X);
  bf16_t* Xk = (bf16_t*)alloc(SZ_X);
  bf16_t* Xv = (bf16_t*)alloc(SZ_X);
  bf16_t* Xr = (bf16_t*)alloc(SZ_X);
  bf16_t* Wqb  = (bf16_t*)alloc(SZ_W);
  bf16_t* Wkb  = (bf16_t*)alloc(SZ_W);
  bf16_t* Wvb  = (bf16_t*)alloc(SZ_W);
  bf16_t* Wrkb = (bf16_t*)alloc(SZ_W);
  bf16_t* Wrvb = (bf16_t*)alloc(SZ_W);
  bf16_t* Wob  = (bf16_t*)alloc(SZ_W);
  bf16_t* qh   = (bf16_t*)alloc(SZ_X);
  bf16_t* kh   = (bf16_t*)alloc(SZ_X);
  bf16_t* rkh  = (bf16_t*)alloc(SZ_X);
  bf16_t* vTh  = (bf16_t*)alloc(SZ_X);
  bf16_t* rvTh = (bf16_t*)alloc(SZ_X);
  bf16_t* xh   = (bf16_t*)alloc(SZ_X);
  (void)Xk; (void)Xv; (void)Xr; (void)Wkb; (void)Wvb; (void)Wrkb; (void)Wrvb;
  (void)kh; (void)rkh; (void)vTh; (void)rvTh;

  // f32 -> bf16
  cvt_multi<<<dim3(4096, 4), 256, 0, stream>>>(query, key_, value, weak, nullptr, nullptr,
                                               Xq, Xk, Xv, Xr, nullptr, nullptr,
                                               NB * SEQ * DMODEL);
  cvt_multi<<<dim3(1024, 6), 256, 0, stream>>>(Wq, Wk, Wv, Wrk, Wrv, Wo,
                                               Wqb, Wkb, Wvb, Wrkb, Wrvb, Wob,
                                               DMODEL * DMODEL);

  // all 5 projections in one grouped dispatch (1280 blocks, 128x128 tiles)
  proj_gemm<<<dim3(1280), 256, 0, stream>>>(Xq, Wqb, qh, bq, bk, bv, brk, brv);

  // fused dual attention: 1024 blocks
  attn_kernel<<<dim3(1024), 256, 0, stream>>>(qh, kh, rkh, vTh, rvTh, mask, xh);

  // output projection -> f32 d_out (256 blocks, 128x128 tiles)
  out_gemm<<<dim3(256), 256, 0, stream>>>(xh, Wob, bo, (float*)d_out);
}

// Round 7
// 170.402 us; speedup vs baseline: 1.0999x; 1.0999x over previous
//
#include <hip/hip_runtime.h>
#include <stdint.h>

#define NB 4
#define NH 16
#define DKH 64
#define DMODEL 1024
#define SEQ 1024
#define SCALE 0.125f
#define NEG_INF -1.0e9f
#define K2E 0.18033688011112042f  // SCALE * log2(e): softmax in exp2 domain

typedef __bf16 bf16_t;
typedef __bf16 bf16x8 __attribute__((ext_vector_type(8)));
typedef __bf16 bf16x4v __attribute__((ext_vector_type(4)));
typedef float f32x4 __attribute__((ext_vector_type(4)));

typedef const uint32_t __attribute__((address_space(1)))* gas_ptr;
typedef uint32_t __attribute__((address_space(3)))* las_ptr;

// async global->LDS, 16B per lane, dest = wave-uniform base + lane*16
__device__ __forceinline__ void gload_lds16(const void* g, void* l) {
  __builtin_amdgcn_global_load_lds((gas_ptr)g, (las_ptr)l, 16, 0, 0);
}

// T2 XOR swizzle for [R][64] bf16 tiles (128B rows): element col ^= (row&7)<<3.
// Staging keeps LDS dest linear and pre-swizzles the GLOBAL source column;
// all LDS reads / reg->LDS writes apply the same XOR (both-sides involution).
// Proven: SQ_LDS_BANK_CONFLICT 1.99e7 -> 0 (R1->R2).
//
// __launch_bounds__ NOTE (R4 post-mortem): (256,4) squeezed to 64 VGPR and
// spilled (~230MB scratch, WRITE_SIZE 8->118MB). (256,2) proven sane.
//
// R6 post-mortem: interleaving vis/rel branch state in registers HURT
// (88->95.7us) -- keep branches sequential; the win axis is LDS traffic
// per q-row (this round: 32 q-rows/wave sharing one K/V fragment read).

// ---------------- f32 -> bf16 conversion (select tensor by blockIdx.y) ----
__global__ void cvt_multi(const float* __restrict__ i0, const float* __restrict__ i1,
                          const float* __restrict__ i2, const float* __restrict__ i3,
                          const float* __restrict__ i4, const float* __restrict__ i5,
                          bf16_t* o0, bf16_t* o1, bf16_t* o2, bf16_t* o3, bf16_t* o4, bf16_t* o5,
                          int n) {
  const int t = blockIdx.y;
  const float* in = (t == 0) ? i0 : (t == 1) ? i1 : (t == 2) ? i2 : (t == 3) ? i3 : (t == 4) ? i4 : i5;
  bf16_t* out = (t == 0) ? o0 : (t == 1) ? o1 : (t == 2) ? o2 : (t == 3) ? o3 : (t == 4) ? o4 : o5;
  const int idx = (blockIdx.x * 256 + threadIdx.x) * 4;
  if (idx >= n) return;
  const float4 v = *(const float4*)(in + idx);
  bf16x4v p;
  p[0] = (bf16_t)v.x; p[1] = (bf16_t)v.y; p[2] = (bf16_t)v.z; p[3] = (bf16_t)v.w;
  *(bf16x4v*)(out + idx) = p;
}

// ---------------- 128x128-tile GEMM core (m97 structure) -------------------
// Y = A @ W^T (+bias). 4 waves (2x2), each owns 64x64; acc[4][4]; BK=64.
// MODE 0: bf16 head-split [B,H,L,DK]; MODE 1: bf16 [B,H,DK,L]; MODE 2: f32.
#define NXE ((size_t)NB * SEQ * DMODEL)      // elements per X/out segment
#define NWE ((size_t)DMODEL * DMODEL)

template<int MODE>
__device__ __forceinline__ void gemm128_body(
    const bf16_t* __restrict__ A, const bf16_t* __restrict__ W,
    const float* __restrict__ bias, void* __restrict__ outp,
    int m0, int n0, bf16_t* As, bf16_t* Bs) {
  const int tid = threadIdx.x;
  const int lane = tid & 63;
  const int w = tid >> 6;
  const int wm = w >> 1, wn = w & 1;
  const int g = lane >> 4, c = lane & 15;
  const int lrow = lane >> 3;
  const int lcol = ((lane & 7) * 8) ^ ((lane >> 3) << 3);  // pre-swizzled source col
  const int sc = (c & 7) << 3;                             // read-side XOR

  f32x4 acc[4][4] = {};

  for (int kt = 0; kt < DMODEL; kt += 64) {
#pragma unroll
    for (int p = 0; p < 4; ++p) {
      const int row = w * 32 + p * 8;
      gload_lds16(A + (size_t)(m0 + row + lrow) * DMODEL + kt + lcol, &As[row * 64]);
      gload_lds16(W + (size_t)(n0 + row + lrow) * DMODEL + kt + lcol, &Bs[row * 64]);
    }
    __syncthreads();
    bf16x8 af[4][2], bfr[4][2];
#pragma unroll
    for (int i = 0; i < 4; ++i)
#pragma unroll
      for (int kk = 0; kk < 2; ++kk) {
        af[i][kk]  = *(const bf16x8*)&As[(wm * 64 + i * 16 + c) * 64 + ((kk * 32 + g * 8) ^ sc)];
        bfr[i][kk] = *(const bf16x8*)&Bs[(wn * 64 + i * 16 + c) * 64 + ((kk * 32 + g * 8) ^ sc)];
      }
#pragma unroll
    for (int i = 0; i < 4; ++i)
#pragma unroll
      for (int j = 0; j < 4; ++j) {
        acc[i][j] = __builtin_amdgcn_mfma_f32_16x16x32_bf16(af[i][0], bfr[j][0], acc[i][j], 0, 0, 0);
        acc[i][j] = __builtin_amdgcn_mfma_f32_16x16x32_bf16(af[i][1], bfr[j][1], acc[i][j], 0, 0, 0);
      }
    __syncthreads();
  }

  float bv4[4];
#pragma unroll
  for (int j = 0; j < 4; ++j) bv4[j] = bias[n0 + wn * 64 + j * 16 + c];

#pragma unroll
  for (int i = 0; i < 4; ++i) {
    const int mrow = m0 + wm * 64 + i * 16 + g * 4;   // C-layout: row = g*4 + r
    const int b_ = mrow >> 10, l_ = mrow & 1023;
#pragma unroll
    for (int j = 0; j < 4; ++j) {
      const int n = n0 + wn * 64 + j * 16 + c;        // C-layout: col = lane&15
      if (MODE == 2) {
        float* o = (float*)outp;
#pragma unroll
        for (int r = 0; r < 4; ++r)
          o[(size_t)(mrow + r) * DMODEL + n] = acc[i][j][r] + bv4[j];
      } else if (MODE == 0) {
        bf16_t* o = (bf16_t*)outp;
        const int h_ = n >> 6, dk_ = n & 63;
#pragma unroll
        for (int r = 0; r < 4; ++r)
          o[((size_t)(b_ * NH + h_) * SEQ + l_ + r) * DKH + dk_] =
              (bf16_t)(acc[i][j][r] + bv4[j]);
      } else { // MODE 1: transposed [B,H,DK,L]; 4 consecutive l -> packed 8B store
        bf16_t* o = (bf16_t*)outp;
        const int h_ = n >> 6, dk_ = n & 63;
        bf16x4v pk;
#pragma unroll
        for (int r = 0; r < 4; ++r) pk[r] = (bf16_t)(acc[i][j][r] + bv4[j]);
        *(bf16x4v*)&o[((size_t)(b_ * NH + h_) * DKH + dk_) * SEQ + l_] = pk;
      }
    }
  }
}

// grouped projection: 5 segments x (32 m-tiles x 8 n-tiles) = 1280 blocks
__global__ void __launch_bounds__(256, 2)
proj_gemm(const bf16_t* __restrict__ Xbase, const bf16_t* __restrict__ Wbase,
          bf16_t* __restrict__ Obase,
          const float* __restrict__ b0, const float* __restrict__ b1,
          const float* __restrict__ b2, const float* __restrict__ b3,
          const float* __restrict__ b4) {
  __shared__ bf16_t As[128 * 64];
  __shared__ bf16_t Bs[128 * 64];
  const int bid = blockIdx.x;
  const int lid = (bid & 7) * 160 + (bid >> 3);   // T1 swizzle (1280 % 8 == 0)
  const int seg = lid >> 8;                       // 0..4
  const int rr = lid & 255;
  const int m0 = (rr >> 3) * 128, n0 = (rr & 7) * 128;

  const bf16_t* A = Xbase + (size_t)((seg < 3) ? seg : 3) * NXE;
  const bf16_t* W = Wbase + (size_t)seg * NWE;
  const int ooff = (seg == 0) ? 0 : (seg == 1) ? 1 : (seg == 2) ? 3 : (seg == 3) ? 2 : 4;
  bf16_t* out = Obase + (size_t)ooff * NXE;
  const float* bias = (seg == 0) ? b0 : (seg == 1) ? b1 : (seg == 2) ? b2 : (seg == 3) ? b3 : b4;

  if (seg == 2 || seg == 4) gemm128_body<1>(A, W, bias, out, m0, n0, As, Bs);
  else                      gemm128_body<0>(A, W, bias, out, m0, n0, As, Bs);
}

// output projection -> f32 d_out: 32 x 8 = 256 blocks
__global__ void __launch_bounds__(256, 2)
out_gemm(const bf16_t* __restrict__ A, const bf16_t* __restrict__ W,
         const float* __restrict__ bias, float* __restrict__ out) {
  __shared__ bf16_t As[128 * 64];
  __shared__ bf16_t Bs[128 * 64];
  const int bid = blockIdx.x;
  const int lid = (bid & 7) * 32 + (bid >> 3);    // T1 swizzle (256 % 8 == 0)
  const int m0 = (lid >> 3) * 128, n0 = (lid & 7) * 128;
  gemm128_body<2>(A, W, bias, out, m0, n0, As, Bs);
}

// ---------------- fused dual flash attention (swapped QK^T, 32 q/wave) -----
// S^T = mfma(A=K, B=Q): lane (g,c) holds S[kv=f*16+g*4+r][q=c]. Wave owns 32
// q-rows as TWO 16-col Q fragments -> one set of K/V fragment reads serves
// both halves (halves LDS traffic per q-row vs R5). Branches sequential (R6
// lesson). P per half round-trips per-wave LDS; PV: O^T = mfma(A=V^T, B=P).
__device__ __forceinline__ void attn_step(
    const bf16_t* __restrict__ Kt, const bf16_t* __restrict__ Vt,
    bf16_t* __restrict__ Pw, const bf16x8 (&qf)[2][2], const int4 (&mk)[4],
    float (&m_s)[2], float (&l_s)[2], f32x4 (&o_s)[2][4], int lane) {
  const int g = lane >> 4, c = lane & 15;
  const int sc = (c & 7) << 3;

  f32x4 s[2][4];
  {
    bf16x8 kfr[4][2];
#pragma unroll
    for (int f = 0; f < 4; ++f) {
      kfr[f][0] = *(const bf16x8*)&Kt[(f * 16 + c) * 64 + ((g * 8) ^ sc)];
      kfr[f][1] = *(const bf16x8*)&Kt[(f * 16 + c) * 64 + ((32 + g * 8) ^ sc)];
    }
#pragma unroll
    for (int i = 0; i < 2; ++i)
#pragma unroll
      for (int f = 0; f < 4; ++f) {
        f32x4 a = {0.f, 0.f, 0.f, 0.f};
        a = __builtin_amdgcn_mfma_f32_16x16x32_bf16(kfr[f][0], qf[i][0], a, 0, 0, 0);
        a = __builtin_amdgcn_mfma_f32_16x16x32_bf16(kfr[f][1], qf[i][1], a, 0, 0, 0);
        s[i][f] = a;
      }
  } // kfr dead -> caps register peak

  // mask + scale into exp2 domain (masked -> NEG_INF; kv=0 always valid)
#pragma unroll
  for (int i = 0; i < 2; ++i)
#pragma unroll
    for (int f = 0; f < 4; ++f) {
      const int4 m4 = mk[f];
      s[i][f][0] = (m4.x == 0) ? NEG_INF : s[i][f][0] * K2E;
      s[i][f][1] = (m4.y == 0) ? NEG_INF : s[i][f][1] * K2E;
      s[i][f][2] = (m4.z == 0) ? NEG_INF : s[i][f][2] * K2E;
      s[i][f][3] = (m4.w == 0) ? NEG_INF : s[i][f][3] * K2E;
    }

  // per-half online softmax (independent chains -> ILP)
#pragma unroll
  for (int i = 0; i < 2; ++i) {
    float tm = fmaxf(fmaxf(s[i][0][0], s[i][0][1]), fmaxf(s[i][0][2], s[i][0][3]));
#pragma unroll
    for (int f = 1; f < 4; ++f)
      tm = fmaxf(tm, fmaxf(fmaxf(s[i][f][0], s[i][f][1]), fmaxf(s[i][f][2], s[i][f][3])));
    tm = fmaxf(tm, __shfl_xor(tm, 16));
    tm = fmaxf(tm, __shfl_xor(tm, 32));
    const float mnew = fmaxf(m_s[i], tm);
    const float sf = __builtin_amdgcn_exp2f(m_s[i] - mnew);
    m_s[i] = mnew;
    float pf = 0.f;
#pragma unroll
    for (int f = 0; f < 4; ++f) {
      bf16x4v pk;
#pragma unroll
      for (int r = 0; r < 4; ++r) {
        const float p = __builtin_amdgcn_exp2f(s[i][f][r] - mnew);
        pf += p;
        pk[r] = (bf16_t)p;
      }
      *(bf16x4v*)&Pw[i * 1024 + c * 64 + ((f * 16 + g * 4) ^ sc)] = pk;
    }
    l_s[i] = l_s[i] * sf + pf;
#pragma unroll
    for (int jd = 0; jd < 4; ++jd)
#pragma unroll
      for (int r = 0; r < 4; ++r) o_s[i][jd][r] *= sf;
  }

  // O^T += V^T @ P : V fragment reads SHARED across both q-halves
  bf16x8 pa[2][2];
#pragma unroll
  for (int i = 0; i < 2; ++i) {
    pa[i][0] = *(const bf16x8*)&Pw[i * 1024 + c * 64 + ((g * 8) ^ sc)];
    pa[i][1] = *(const bf16x8*)&Pw[i * 1024 + c * 64 + ((32 + g * 8) ^ sc)];
  }
#pragma unroll
  for (int jd = 0; jd < 4; ++jd) {
    const bf16x8 v0 = *(const bf16x8*)&Vt[(jd * 16 + c) * 64 + ((g * 8) ^ sc)];
    const bf16x8 v1 = *(const bf16x8*)&Vt[(jd * 16 + c) * 64 + ((32 + g * 8) ^ sc)];
#pragma unroll
    for (int i = 0; i < 2; ++i) {
      o_s[i][jd] = __builtin_amdgcn_mfma_f32_16x16x32_bf16(v0, pa[i][0], o_s[i][jd], 0, 0, 0);
      o_s[i][jd] = __builtin_amdgcn_mfma_f32_16x16x32_bf16(v1, pa[i][1], o_s[i][jd], 0, 0, 0);
    }
  }
}

__global__ void __launch_bounds__(256, 2)
attn_kernel(const bf16_t* __restrict__ q, const bf16_t* __restrict__ k,
            const bf16_t* __restrict__ rk, const bf16_t* __restrict__ vT,
            const bf16_t* __restrict__ rvT, const int* __restrict__ mask,
            bf16_t* __restrict__ x) {
  __shared__ bf16_t Ks[64 * 64], RKs[64 * 64], Vs[64 * 64], RVs[64 * 64]; // 32KB
  __shared__ bf16_t Ps[4][2][16 * 64];                                   // 16KB

  const int tid = threadIdx.x;
  const int lane = tid & 63;
  const int w = tid >> 6;
  const int g = lane >> 4, c = lane & 15;
  const int bid = blockIdx.x;
  const int lid = (bid & 7) * 64 + (bid >> 3);   // T1 swizzle (512 % 8 == 0)
  const int qt = lid & 7;
  const int bh = lid >> 3;
  const int b = bh >> 4, h = bh & 15;
  const int q0 = qt * 128;

  const bf16_t* qp = q + (size_t)bh * SEQ * DKH;
  const bf16_t* kp = k + (size_t)bh * SEQ * DKH;
  const bf16_t* rkp = rk + (size_t)bh * SEQ * DKH;
  const bf16_t* vp = vT + (size_t)bh * DKH * SEQ;
  const bf16_t* rvp = rvT + (size_t)bh * DKH * SEQ;
  const int* mp = mask + b * SEQ;
  const int lrow = lane >> 3;
  const int lcol = ((lane & 7) * 8) ^ ((lane >> 3) << 3);  // pre-swizzled source col

  // Q fragments in registers: wave owns 32 q-rows as two 16-col B-fragments
  bf16x8 qf[2][2];
#pragma unroll
  for (int i = 0; i < 2; ++i)
#pragma unroll
    for (int kk = 0; kk < 2; ++kk)
      qf[i][kk] = *(const bf16x8*)(qp + (size_t)(q0 + w * 32 + i * 16 + c) * DKH + kk * 32 + g * 8);

  f32x4 ov[2][4] = {}, orl[2][4] = {};
  float mv[2] = {NEG_INF, NEG_INF}, mr[2] = {NEG_INF, NEG_INF};
  float lv[2] = {0.f, 0.f}, lr[2] = {0.f, 0.f};

  for (int t = 0; t < 16; ++t) {
    const int kv0 = t * 64;
    if (t) __syncthreads();   // previous compute done before overwriting tiles
#pragma unroll
    for (int p = 0; p < 2; ++p) {
      const int row = w * 16 + p * 8;
      gload_lds16(kp  + (size_t)(kv0 + row + lrow) * DKH + lcol, &Ks[row * 64]);
      gload_lds16(rkp + (size_t)(kv0 + row + lrow) * DKH + lcol, &RKs[row * 64]);
      gload_lds16(vp  + (size_t)(row + lrow) * SEQ + kv0 + lcol, &Vs[row * 64]);
      gload_lds16(rvp + (size_t)(row + lrow) * SEQ + kv0 + lcol, &RVs[row * 64]);
    }
    __syncthreads();          // tiles ready

    int4 mk4[4];
#pragma unroll
    for (int f = 0; f < 4; ++f) mk4[f] = *(const int4*)&mp[kv0 + f * 16 + g * 4];

    attn_step(Ks,  Vs,  &Ps[w][0][0], qf, mk4, mv, lv, ov,  lane);
    attn_step(RKs, RVs, &Ps[w][0][0], qf, mk4, mr, lr, orl, lane);
  }

  // denominators: reduce per-lane partials across the 4 g-groups
#pragma unroll
  for (int i = 0; i < 2; ++i) {
    lv[i] += __shfl_xor(lv[i], 16); lv[i] += __shfl_xor(lv[i], 32);
    lr[i] += __shfl_xor(lr[i], 16); lr[i] += __shfl_xor(lr[i], 32);
  }

  bf16_t* xb = x + (size_t)b * SEQ * DMODEL + (size_t)h * DKH;
#pragma unroll
  for (int i = 0; i < 2; ++i) {
    const float rlv = 1.0f / lv[i], rlr = 1.0f / lr[i];
    const int qrow = q0 + w * 32 + i * 16 + c;
#pragma unroll
    for (int jd = 0; jd < 4; ++jd) {
      bf16x4v pk;
#pragma unroll
      for (int r = 0; r < 4; ++r)
        pk[r] = (bf16_t)(ov[i][jd][r] * rlv + orl[i][jd][r] * rlr);
      *(bf16x4v*)&xb[(size_t)qrow * DMODEL + jd * 16 + g * 4] = pk;
    }
  }
}

// ---------------- host launch ---------------------------------------------
extern "C" void kernel_launch(void* const* d_in, const int* in_sizes, int n_in,
                              void* d_out, int out_size, void* d_ws, size_t ws_size,
                              hipStream_t stream) {
  (void)in_sizes; (void)n_in; (void)out_size; (void)ws_size;
  const float* query = (const float*)d_in[0];
  const float* key_  = (const float*)d_in[1];
  const float* value = (const float*)d_in[2];
  const float* weak  = (const float*)d_in[3];
  const int*   mask  = (const int*)d_in[4];
  const float* Wq  = (const float*)d_in[5];  const float* bq  = (const float*)d_in[6];
  const float* Wk  = (const float*)d_in[7];  const float* bk  = (const float*)d_in[8];
  const float* Wv  = (const float*)d_in[9];  const float* bv  = (const float*)d_in[10];
  const float* Wrk = (const float*)d_in[11]; const float* brk = (const float*)d_in[12];
  const float* Wrv = (const float*)d_in[13]; const float* brv = (const float*)d_in[14];
  const float* Wo  = (const float*)d_in[15]; const float* bo  = (const float*)d_in[16];

  char* ws = (char*)d_ws;
  size_t off = 0;
  auto alloc = [&](size_t bytes) {
    void* p = ws + off;
    off += (bytes + 255) & ~(size_t)255;
    return p;
  };
  const size_t SZ_X = NXE * sizeof(bf16_t); // 8 MB (256-aligned -> contiguous)
  const size_t SZ_W = NWE * sizeof(bf16_t); // 2 MB

  // X segments contiguous (q,k,v,r), W segments contiguous (q,k,v,rk,rv,o),
  // proj outputs contiguous (qh,kh,rkh,vTh,rvTh) -- proj_gemm indexes by base.
  bf16_t* Xq = (bf16_t*)alloc(SZ_X);
  bf16_t* Xk = (bf16_t*)alloc(SZ_X);
  bf16_t* Xv = (bf16_t*)alloc(SZ_X);
  bf16_t* Xr = (bf16_t*)alloc(SZ_X);
  bf16_t* Wqb  = (bf16_t*)alloc(SZ_W);
  bf16_t* Wkb  = (bf16_t*)alloc(SZ_W);
  bf16_t* Wvb  = (bf16_t*)alloc(SZ_W);
  bf16_t* Wrkb = (bf16_t*)alloc(SZ_W);
  bf16_t* Wrvb = (bf16_t*)alloc(SZ_W);
  bf16_t* Wob  = (bf16_t*)alloc(SZ_W);
  bf16_t* qh   = (bf16_t*)alloc(SZ_X);
  bf16_t* kh   = (bf16_t*)alloc(SZ_X);
  bf16_t* rkh  = (bf16_t*)alloc(SZ_X);
  bf16_t* vTh  = (bf16_t*)alloc(SZ_X);
  bf16_t* rvTh = (bf16_t*)alloc(SZ_X);
  bf16_t* xh   = (bf16_t*)alloc(SZ_X);
  (void)Xk; (void)Xv; (void)Xr; (void)Wkb; (void)Wvb; (void)Wrkb; (void)Wrvb;
  (void)kh; (void)rkh; (void)vTh; (void)rvTh;

  // f32 -> bf16
  cvt_multi<<<dim3(4096, 4), 256, 0, stream>>>(query, key_, value, weak, nullptr, nullptr,
                                               Xq, Xk, Xv, Xr, nullptr, nullptr,
                                               NB * SEQ * DMODEL);
  cvt_multi<<<dim3(1024, 6), 256, 0, stream>>>(Wq, Wk, Wv, Wrk, Wrv, Wo,
                                               Wqb, Wkb, Wvb, Wrkb, Wrvb, Wob,
                                               DMODEL * DMODEL);

  // all 5 projections in one grouped dispatch (1280 blocks, 128x128 tiles)
  proj_gemm<<<dim3(1280), 256, 0, stream>>>(Xq, Wqb, qh, bq, bk, bv, brk, brv);

  // fused dual attention: 512 blocks (q-tile 128, 32 q-rows/wave)
  attn_kernel<<<dim3(512), 256, 0, stream>>>(qh, kh, rkh, vTh, rvTh, mask, xh);

  // output projection -> f32 d_out (256 blocks, 128x128 tiles)
  out_gemm<<<dim3(256), 256, 0, stream>>>(xh, Wob, bo, (float*)d_out);
}